// Round 2
// baseline (312.703 us; speedup 1.0000x reference)
//
#include <hip/hip_runtime.h>
#include <math.h>

// ---------------------------------------------------------------------------
// Pass 1a: per-batch displacement scales.
// sc[2n]   = cos(ang)*amp*(2/3)/(W-1)   (the /3 is the channel mean)
// sc[2n+1] = sin(ang)*amp*(2/3)/(H-1)
// ---------------------------------------------------------------------------
__global__ void scales_kernel(const float* __restrict__ amp,
                              const float* __restrict__ ang,
                              float* __restrict__ sc,
                              int N, float invW1, float invH1) {
    int i = threadIdx.x;
    if (i < N) {
        float s, c;
        sincosf(ang[i], &s, &c);
        float a = amp[i] * (2.0f / 3.0f);
        sc[2 * i]     = c * a * invW1;
        sc[2 * i + 1] = s * a * invH1;
    }
}

// ---------------------------------------------------------------------------
// Pass 1b: reduce dmap channels (sum over 3). 4 pixels/thread, float4 I/O.
// rd[p] = dmap[p*3+0]+dmap[p*3+1]+dmap[p*3+2]
// ---------------------------------------------------------------------------
__global__ __launch_bounds__(256) void reduce_dmap_kernel(
    const float* __restrict__ dmap, float* __restrict__ rd, long long npix) {
    long long p0 = ((long long)blockIdx.x * blockDim.x + threadIdx.x) * 4;
    if (p0 + 3 < npix) {
        const float4* src = (const float4*)(dmap + p0 * 3);  // 48B-aligned
        float4 v0 = src[0], v1 = src[1], v2 = src[2];
        float4 s;
        s.x = v0.x + v0.y + v0.z;
        s.y = v0.w + v1.x + v1.y;
        s.z = v1.z + v1.w + v2.x;
        s.w = v2.y + v2.z + v2.w;
        *(float4*)(rd + p0) = s;
    } else {
        for (long long p = p0; p < npix; ++p) {
            const float* s = dmap + p * 3;
            rd[p] = s[0] + s[1] + s[2];
        }
    }
}

// ---------------------------------------------------------------------------
// Reflection, compile-time size: mod uses exact power-of-2 reciprocal.
// ---------------------------------------------------------------------------
template <int S>
__device__ __forceinline__ float reflectc(float x) {
    x += 0.5f;
    constexpr float two = 2.0f * S;
    float q = floorf(x * (1.0f / two));
    x = fmaf(-q, two, x);
    if (x >= (float)S) x = two - x;
    x -= 0.5f;
    return fminf(fmaxf(x, 0.0f), (float)(S - 1));
}

// ---------------------------------------------------------------------------
// Pass 2: main displacement. Grid (W/1024, H, N), 4 px/thread, float4 stores.
// ---------------------------------------------------------------------------
template <int H, int W, int DH, int DW>
__global__ __launch_bounds__(256) void displace_main(
    const float* __restrict__ img,   // N,H,W,3
    const float* __restrict__ rd,    // N,DH,DW  (channel-summed dmap)
    const float* __restrict__ sc,    // N*2 scales
    float* __restrict__ out)         // N,H,W,3
{
    const int n = blockIdx.z;
    const int h = blockIdx.y;
    const int w0 = ((int)blockIdx.x * (int)blockDim.x + (int)threadIdx.x) * 4;
    if (w0 >= W) return;

    // --- row-shared dmap y-interp setup ---
    constexpr float sDH = (float)DH / (float)H;
    constexpr float sDW = (float)DW / (float)W;
    float sy = fmaf((float)h + 0.5f, sDH, -0.5f);
    float fy = floorf(sy);
    float ty = sy - fy;
    int iyf = (int)fy;
    int dy0 = min(max(iyf, 0), DH - 1);
    int dy1 = min(max(iyf + 1, 0), DH - 1);
    const float* r0 = rd + ((long long)n * DH + dy0) * DW;
    const float* r1 = rd + ((long long)n * DH + dy1) * DW;

    const float scx = sc[2 * n];
    const float scy = sc[2 * n + 1];
    const float* ibase = img + (long long)n * H * W * 3;
    const float gyb = fmaf((float)h, 2.0f / (float)(H - 1), -1.0f);

    float acc[12];

    #pragma unroll
    for (int i = 0; i < 4; ++i) {
        int w = w0 + i;
        // dmap x-interp
        float sx = fmaf((float)w + 0.5f, sDW, -0.5f);
        float fx = floorf(sx);
        float tx = sx - fx;
        int ixf = (int)fx;
        int dx0 = min(max(ixf, 0), DW - 1);
        int dx1 = min(max(ixf + 1, 0), DW - 1);
        float a0 = r0[dx0], b0 = r0[dx1];
        float a1 = r1[dx0], b1 = r1[dx1];
        float m0 = fmaf(b0 - a0, tx, a0);
        float m1 = fmaf(b1 - a1, tx, a1);
        float ds = fmaf(m1 - m0, ty, m0);

        // sampling grid
        float gx = fmaf((float)w, 2.0f / (float)(W - 1), -1.0f) + ds * scx;
        float gy = gyb + ds * scy;

        // unnormalize + reflect
        float ix = fmaf(gx + 1.0f, (float)W * 0.5f, -0.5f);
        float iy = fmaf(gy + 1.0f, (float)H * 0.5f, -0.5f);
        ix = reflectc<W>(ix);
        iy = reflectc<H>(iy);

        // bilinear gather
        float x0f = floorf(ix), y0f = floorf(iy);
        float wx = ix - x0f, wy = iy - y0f;
        int ix0 = min((int)x0f, W - 1);
        int ix1 = min((int)x0f + 1, W - 1);
        int iy0 = min((int)y0f, H - 1);
        int iy1 = min((int)y0f + 1, H - 1);

        const float* Ia = ibase + ((long long)iy0 * W + ix0) * 3;
        const float* Ib = ibase + ((long long)iy0 * W + ix1) * 3;
        const float* Ic = ibase + ((long long)iy1 * W + ix0) * 3;
        const float* Id = ibase + ((long long)iy1 * W + ix1) * 3;

        float wa = (1.0f - wx) * (1.0f - wy);
        float wb = wx * (1.0f - wy);
        float wc = (1.0f - wx) * wy;
        float wd = wx * wy;

        #pragma unroll
        for (int c = 0; c < 3; ++c) {
            acc[3 * i + c] = Ia[c] * wa + Ib[c] * wb + Ic[c] * wc + Id[c] * wd;
        }
    }

    float4* o = (float4*)(out + (((long long)n * H + h) * W + w0) * 3);
    o[0] = make_float4(acc[0], acc[1], acc[2], acc[3]);
    o[1] = make_float4(acc[4], acc[5], acc[6], acc[7]);
    o[2] = make_float4(acc[8], acc[9], acc[10], acc[11]);
}

// ---------------------------------------------------------------------------
// Fallback (generic dims or insufficient ws): round-0 style single kernel.
// ---------------------------------------------------------------------------
__device__ __forceinline__ float reflect_dyn(float x, float size) {
    x += 0.5f;
    float two = 2.0f * size;
    x = x - floorf(x / two) * two;
    if (x >= size) x = two - x;
    x -= 0.5f;
    return fminf(fmaxf(x, 0.0f), size - 1.0f);
}

__global__ __launch_bounds__(256) void displace_fallback(
    const float* __restrict__ img, const float* __restrict__ dmap,
    const float* __restrict__ amp, const float* __restrict__ ang,
    float* __restrict__ out, int N, int H, int W, int DH, int DW)
{
    long long idx = (long long)blockIdx.x * blockDim.x + threadIdx.x;
    long long total = (long long)N * H * W;
    if (idx >= total) return;
    int w = (int)(idx % W);
    long long t = idx / W;
    int h = (int)(t % H);
    int n = (int)(t / H);

    float sx = (w + 0.5f) * ((float)DW / (float)W) - 0.5f;
    float sy = (h + 0.5f) * ((float)DH / (float)H) - 0.5f;
    float fx = floorf(sx), fy = floorf(sy);
    float tx = sx - fx, ty = sy - fy;
    int dx0 = max(0, min(DW - 1, (int)fx));
    int dx1 = max(0, min(DW - 1, (int)fx + 1));
    int dy0 = max(0, min(DH - 1, (int)fy));
    int dy1 = max(0, min(DH - 1, (int)fy + 1));
    const float* dbase = dmap + (long long)n * DH * DW * 3;
    const float* p00 = dbase + ((long long)dy0 * DW + dx0) * 3;
    const float* p01 = dbase + ((long long)dy0 * DW + dx1) * 3;
    const float* p10 = dbase + ((long long)dy1 * DW + dx0) * 3;
    const float* p11 = dbase + ((long long)dy1 * DW + dx1) * 3;
    float m00 = p00[0] + p00[1] + p00[2];
    float m01 = p01[0] + p01[1] + p01[2];
    float m10 = p10[0] + p10[1] + p10[2];
    float m11 = p11[0] + p11[1] + p11[2];
    float dmv = ((m00 * (1.0f - tx) + m01 * tx) * (1.0f - ty)
               + (m10 * (1.0f - tx) + m11 * tx) * ty) * (1.0f / 3.0f);
    float a = amp[n], an = ang[n], sa, ca;
    sincosf(an, &sa, &ca);
    float d = dmv * a;
    float gx = -1.0f + 2.0f * (float)w / (float)(W - 1) + ca * d * (2.0f / (float)(W - 1));
    float gy = -1.0f + 2.0f * (float)h / (float)(H - 1) + sa * d * (2.0f / (float)(H - 1));
    float ix = ((gx + 1.0f) * (float)W - 1.0f) * 0.5f;
    float iy = ((gy + 1.0f) * (float)H - 1.0f) * 0.5f;
    ix = reflect_dyn(ix, (float)W);
    iy = reflect_dyn(iy, (float)H);
    float x0f = floorf(ix), y0f = floorf(iy);
    float wx = ix - x0f, wy = iy - y0f;
    int ix0 = min((int)x0f, W - 1);
    int ix1 = min((int)x0f + 1, W - 1);
    int iy0 = min((int)y0f, H - 1);
    int iy1 = min((int)y0f + 1, H - 1);
    const float* ibase = img + (long long)n * H * W * 3;
    const float* Ia = ibase + ((long long)iy0 * W + ix0) * 3;
    const float* Ib = ibase + ((long long)iy0 * W + ix1) * 3;
    const float* Ic = ibase + ((long long)iy1 * W + ix0) * 3;
    const float* Id = ibase + ((long long)iy1 * W + ix1) * 3;
    float wa = (1.0f - wx) * (1.0f - wy);
    float wb = wx * (1.0f - wy);
    float wc = (1.0f - wx) * wy;
    float wd = wx * wy;
    float* o = out + idx * 3;
    #pragma unroll
    for (int c = 0; c < 3; ++c)
        o[c] = Ia[c] * wa + Ib[c] * wb + Ic[c] * wc + Id[c] * wd;
}

extern "C" void kernel_launch(void* const* d_in, const int* in_sizes, int n_in,
                              void* d_out, int out_size, void* d_ws, size_t ws_size,
                              hipStream_t stream) {
    const float* img  = (const float*)d_in[0];
    const float* dmap = (const float*)d_in[1];
    const float* amp  = (const float*)d_in[2];
    const float* ang  = (const float*)d_in[3];
    float* out = (float*)d_out;

    int N = in_sizes[2];
    long long hw  = (long long)in_sizes[0] / ((long long)N * 3);
    int H = (int)llround(sqrt((double)hw));
    int W = H;
    long long dhw = (long long)in_sizes[1] / ((long long)N * 3);
    int DH = (int)llround(sqrt((double)dhw));
    int DW = DH;

    // workspace layout: [0, 256B): scales (2*N floats); [256B, ...): reduced dmap
    size_t need = 256 + (size_t)N * DH * DW * sizeof(float);

    if (H == 1024 && W == 1024 && DH == 512 && DW == 512 && ws_size >= need) {
        float* sc = (float*)d_ws;
        float* rd = (float*)((char*)d_ws + 256);

        scales_kernel<<<1, 64, 0, stream>>>(amp, ang, sc, N,
                                            1.0f / (float)(W - 1),
                                            1.0f / (float)(H - 1));

        long long npix = (long long)N * DH * DW;
        long long rthreads = (npix + 3) / 4;
        int rgrid = (int)((rthreads + 255) / 256);
        reduce_dmap_kernel<<<rgrid, 256, 0, stream>>>(dmap, rd, npix);

        dim3 grid(W / (256 * 4), H, N);
        displace_main<1024, 1024, 512, 512><<<grid, 256, 0, stream>>>(img, rd, sc, out);
    } else {
        long long total = (long long)N * H * W;
        int block = 256;
        long long grid = (total + block - 1) / block;
        displace_fallback<<<(dim3)(unsigned)grid, block, 0, stream>>>(
            img, dmap, amp, ang, out, N, H, W, DH, DW);
    }
}

// Round 3
// 242.751 us; speedup vs baseline: 1.2882x; 1.2882x over previous
//
#include <hip/hip_runtime.h>
#include <math.h>

// ---------------------------------------------------------------------------
// Prep: rd[p] = dmap[p*3]+dmap[p*3+1]+dmap[p*3+2]  (lane-contiguous reads,
// coalesced writes). Block 0 also computes per-batch scales:
//   sc[2n]   = cos(ang)*amp*(1/3)*(W/(W-1))   (folded unnormalize, /3 = mean)
//   sc[2n+1] = sin(ang)*amp*(1/3)*(H/(H-1))
// ---------------------------------------------------------------------------
__global__ __launch_bounds__(256) void prep_kernel(
    const float* __restrict__ dmap, const float* __restrict__ amp,
    const float* __restrict__ ang, float* __restrict__ sc,
    float* __restrict__ rd, long long npix, int N, float fx, float fy) {
    long long p = (long long)blockIdx.x * 256 + threadIdx.x;
    if (p < npix) {
        const float* s = dmap + p * 3;
        rd[p] = s[0] + s[1] + s[2];
    }
    if (blockIdx.x == 0 && (int)threadIdx.x < N) {
        int i = threadIdx.x;
        float s_, c_;
        sincosf(ang[i], &s_, &c_);
        float a = amp[i] * (1.0f / 3.0f);
        sc[2 * i]     = c_ * a * fx;
        sc[2 * i + 1] = s_ * a * fy;
    }
}

// ---------------------------------------------------------------------------
// Main: H=W=1024, DH=DW=512. One row per 1024-thread block, 1 px/thread
// (lane-contiguous: R0's proven fetch-minimal pattern). XCD swizzle: linear
// block id & 7 selects image -> each XCD streams one image's rows in order,
// keeping the +/-20-row gather reuse inside its 4 MiB L2.
// ---------------------------------------------------------------------------
__global__ __launch_bounds__(1024, 8) void displace_main(
    const float* __restrict__ img,   // N,1024,1024,3
    const float* __restrict__ rd,    // N,512,512 channel-summed dmap
    const float* __restrict__ sc,    // 2*N scales
    float* __restrict__ out)         // N,1024,1024,3
{
    const int lin = (int)blockIdx.y * 1024 + (int)blockIdx.x;
    const int hl  = (lin & 7) * 1024 + (lin >> 3);   // XCD-contiguous rows
    const int n   = hl >> 10;
    const int h   = hl & 1023;
    const int w   = threadIdx.x;

    // row-uniform dmap y setup — parity trick (exact for 2x half-pixel resize)
    const int dy0 = max((h - 1) >> 1, 0);
    const int dy1 = min((h + 1) >> 1, 511);
    const float ty = (h & 1) ? 0.25f : 0.75f;
    const float* r0 = rd + (n * 512 + dy0) * 512;
    const float* r1 = rd + (n * 512 + dy1) * 512;
    const float scx = sc[2 * n];
    const float scy = sc[2 * n + 1];
    const float* ibase = img + (long long)n * (1024 * 1024 * 3);

    // dmap x interp (parity trick)
    const int dx0 = max((w - 1) >> 1, 0);
    const int dx1 = min((w + 1) >> 1, 511);
    const float tx = (w & 1) ? 0.25f : 0.75f;
    float a0 = r0[dx0], b0 = r0[dx1];
    float a1 = r1[dx0], b1 = r1[dx1];
    float m0 = fmaf(b0 - a0, tx, a0);
    float m1 = fmaf(b1 - a1, tx, a1);
    float ds = fmaf(m1 - m0, ty, m0);

    // sample coords + 0.5 (folded): u = w*1024/1023 + ds*sc; |disp| <= ~21 px
    const float C = 1024.0f / 1023.0f;
    float ux = fmaf((float)w, C, ds * scx);
    float uy = fmaf((float)h, C, ds * scy);

    // reflect (single fold valid: u in (-21, 1046) subset of (-2048, 2048))
    ux = fabsf(ux); if (ux >= 1024.0f) ux = 2048.0f - ux;
    uy = fabsf(uy); if (uy >= 1024.0f) uy = 2048.0f - uy;
    float ix = fminf(fmaxf(ux - 0.5f, 0.0f), 1023.0f);
    float iy = fminf(fmaxf(uy - 0.5f, 0.0f), 1023.0f);

    // bilinear gather
    int ix0 = (int)ix;                 // ix >= 0 -> trunc == floor
    int iy0 = (int)iy;
    float wx = ix - (float)ix0;
    float wy = iy - (float)iy0;
    int ix1 = min(ix0 + 1, 1023);
    int iy1 = min(iy0 + 1, 1023);

    const float* Ia = ibase + ((iy0 << 10) + ix0) * 3;
    const float* Ib = ibase + ((iy0 << 10) + ix1) * 3;
    const float* Ic = ibase + ((iy1 << 10) + ix0) * 3;
    const float* Id = ibase + ((iy1 << 10) + ix1) * 3;

    const float wa = (1.0f - wx) * (1.0f - wy);
    const float wb = wx * (1.0f - wy);
    const float wc = (1.0f - wx) * wy;
    const float wd = wx * wy;

    float* o = out + ((hl << 10) + w) * 3;
    o[0] = Ia[0] * wa + Ib[0] * wb + Ic[0] * wc + Id[0] * wd;
    o[1] = Ia[1] * wa + Ib[1] * wb + Ic[1] * wc + Id[1] * wd;
    o[2] = Ia[2] * wa + Ib[2] * wb + Ic[2] * wc + Id[2] * wd;
}

// ---------------------------------------------------------------------------
// Generic fallback (R0 kernel, proven correct/92us) for other shapes.
// ---------------------------------------------------------------------------
__device__ __forceinline__ float reflect_dyn(float x, float size) {
    x += 0.5f;
    float two = 2.0f * size;
    x = x - floorf(x / two) * two;
    if (x >= size) x = two - x;
    x -= 0.5f;
    return fminf(fmaxf(x, 0.0f), size - 1.0f);
}

__global__ __launch_bounds__(256) void displace_fallback(
    const float* __restrict__ img, const float* __restrict__ dmap,
    const float* __restrict__ amp, const float* __restrict__ ang,
    float* __restrict__ out, int N, int H, int W, int DH, int DW)
{
    long long idx = (long long)blockIdx.x * blockDim.x + threadIdx.x;
    long long total = (long long)N * H * W;
    if (idx >= total) return;
    int w = (int)(idx % W);
    long long t = idx / W;
    int h = (int)(t % H);
    int n = (int)(t / H);

    float sx = (w + 0.5f) * ((float)DW / (float)W) - 0.5f;
    float sy = (h + 0.5f) * ((float)DH / (float)H) - 0.5f;
    float fx = floorf(sx), fy = floorf(sy);
    float tx = sx - fx, ty = sy - fy;
    int dx0 = max(0, min(DW - 1, (int)fx));
    int dx1 = max(0, min(DW - 1, (int)fx + 1));
    int dy0 = max(0, min(DH - 1, (int)fy));
    int dy1 = max(0, min(DH - 1, (int)fy + 1));
    const float* dbase = dmap + (long long)n * DH * DW * 3;
    const float* p00 = dbase + ((long long)dy0 * DW + dx0) * 3;
    const float* p01 = dbase + ((long long)dy0 * DW + dx1) * 3;
    const float* p10 = dbase + ((long long)dy1 * DW + dx0) * 3;
    const float* p11 = dbase + ((long long)dy1 * DW + dx1) * 3;
    float m00 = p00[0] + p00[1] + p00[2];
    float m01 = p01[0] + p01[1] + p01[2];
    float m10 = p10[0] + p10[1] + p10[2];
    float m11 = p11[0] + p11[1] + p11[2];
    float dmv = ((m00 * (1.0f - tx) + m01 * tx) * (1.0f - ty)
               + (m10 * (1.0f - tx) + m11 * tx) * ty) * (1.0f / 3.0f);
    float a = amp[n], an = ang[n], sa, ca;
    sincosf(an, &sa, &ca);
    float d = dmv * a;
    float gx = -1.0f + 2.0f * (float)w / (float)(W - 1) + ca * d * (2.0f / (float)(W - 1));
    float gy = -1.0f + 2.0f * (float)h / (float)(H - 1) + sa * d * (2.0f / (float)(H - 1));
    float ixf2 = ((gx + 1.0f) * (float)W - 1.0f) * 0.5f;
    float iyf2 = ((gy + 1.0f) * (float)H - 1.0f) * 0.5f;
    ixf2 = reflect_dyn(ixf2, (float)W);
    iyf2 = reflect_dyn(iyf2, (float)H);
    float x0f = floorf(ixf2), y0f = floorf(iyf2);
    float wx = ixf2 - x0f, wy = iyf2 - y0f;
    int ix0 = min((int)x0f, W - 1);
    int ix1 = min((int)x0f + 1, W - 1);
    int iy0 = min((int)y0f, H - 1);
    int iy1 = min((int)y0f + 1, H - 1);
    const float* ibase = img + (long long)n * H * W * 3;
    const float* Ia = ibase + ((long long)iy0 * W + ix0) * 3;
    const float* Ib = ibase + ((long long)iy0 * W + ix1) * 3;
    const float* Ic = ibase + ((long long)iy1 * W + ix0) * 3;
    const float* Id = ibase + ((long long)iy1 * W + ix1) * 3;
    float wa = (1.0f - wx) * (1.0f - wy);
    float wb = wx * (1.0f - wy);
    float wc = (1.0f - wx) * wy;
    float wd = wx * wy;
    float* o = out + idx * 3;
    #pragma unroll
    for (int c = 0; c < 3; ++c)
        o[c] = Ia[c] * wa + Ib[c] * wb + Ic[c] * wc + Id[c] * wd;
}

extern "C" void kernel_launch(void* const* d_in, const int* in_sizes, int n_in,
                              void* d_out, int out_size, void* d_ws, size_t ws_size,
                              hipStream_t stream) {
    const float* img  = (const float*)d_in[0];
    const float* dmap = (const float*)d_in[1];
    const float* amp  = (const float*)d_in[2];
    const float* ang  = (const float*)d_in[3];
    float* out = (float*)d_out;

    int N = in_sizes[2];
    long long hw  = (long long)in_sizes[0] / ((long long)N * 3);
    int H = (int)llround(sqrt((double)hw));
    int W = H;
    long long dhw = (long long)in_sizes[1] / ((long long)N * 3);
    int DH = (int)llround(sqrt((double)dhw));
    int DW = DH;

    size_t need = 256 + (size_t)N * DH * DW * sizeof(float);

    if (H == 1024 && W == 1024 && DH == 512 && DW == 512 && N <= 256 &&
        ws_size >= need) {
        float* sc = (float*)d_ws;
        float* rd = (float*)((char*)d_ws + 256);

        long long npix = (long long)N * DH * DW;
        int pgrid = (int)((npix + 255) / 256);
        prep_kernel<<<pgrid, 256, 0, stream>>>(
            dmap, amp, ang, sc, rd, npix, N,
            (float)W / (float)(W - 1), (float)H / (float)(H - 1));

        dim3 grid(1024, (unsigned)N);
        displace_main<<<grid, 1024, 0, stream>>>(img, rd, sc, out);
    } else {
        long long total = (long long)N * H * W;
        int block = 256;
        long long grid = (total + block - 1) / block;
        displace_fallback<<<(dim3)(unsigned)grid, block, 0, stream>>>(
            img, dmap, amp, ang, out, N, H, W, DH, DW);
    }
}

// Round 4
// 232.311 us; speedup vs baseline: 1.3461x; 1.0449x over previous
//
#include <hip/hip_runtime.h>
#include <math.h>

// ---------------------------------------------------------------------------
// Prep: rd[p] = dmap[p*3]+dmap[p*3+1]+dmap[p*3+2]  (lane-contiguous reads,
// coalesced writes). Block 0 also computes per-batch scales:
//   sc[2n]   = cos(ang)*amp*(1/3)*(W/(W-1))   (folded unnormalize, /3 = mean)
//   sc[2n+1] = sin(ang)*amp*(1/3)*(H/(H-1))
// ---------------------------------------------------------------------------
__global__ __launch_bounds__(256) void prep_kernel(
    const float* __restrict__ dmap, const float* __restrict__ amp,
    const float* __restrict__ ang, float* __restrict__ sc,
    float* __restrict__ rd, long long npix, int N, float fx, float fy) {
    long long p = (long long)blockIdx.x * 256 + threadIdx.x;
    if (p < npix) {
        const float* s = dmap + p * 3;
        rd[p] = s[0] + s[1] + s[2];
    }
    if (blockIdx.x == 0 && (int)threadIdx.x < N) {
        int i = threadIdx.x;
        float s_, c_;
        sincosf(ang[i], &s_, &c_);
        float a = amp[i] * (1.0f / 3.0f);
        sc[2 * i]     = c_ * a * fx;
        sc[2 * i + 1] = s_ * a * fy;
    }
}

// ---------------------------------------------------------------------------
// Main: H=W=1024, DH=DW=512, N<=8 path. 256-thread blocks; each thread owns
// 4 ROWS at the same w (lane-contiguous per row -> fetch-minimal gathers,
// 4 independent dependency chains per thread -> memory latency hidden).
// Flat-grid decode keeps XCD k on image k with rows ascending (L2 locality).
// ---------------------------------------------------------------------------
__global__ __launch_bounds__(256) void displace_main(
    const float* __restrict__ img,   // N,1024,1024,3
    const float* __restrict__ rd,    // N,512,512 channel-summed dmap
    const float* __restrict__ sc,    // 2*N scales
    float* __restrict__ out)         // N,1024,1024,3
{
    const int lin  = (int)blockIdx.x;
    const int n    = lin & 7;           // XCD k <-> image k (round-robin)
    const int rest = lin >> 3;          // [0, 1024): ascending rows per XCD
    const int h0   = (rest >> 2) << 2;  // row group of 4
    const int w    = ((rest & 3) << 8) + (int)threadIdx.x;

    const float scx = sc[2 * n];
    const float scy = sc[2 * n + 1];
    const float* ibase = img + (long long)n * (1024 * 1024 * 3);
    const float* rbase = rd + n * (512 * 512);

    // x-side dmap interp setup: shared by all 4 rows (parity trick, exact)
    const int dx0 = max((w - 1) >> 1, 0);
    const int dx1 = min((w + 1) >> 1, 511);
    const float tx = (w & 1) ? 0.25f : 0.75f;
    const float C = 1024.0f / 1023.0f;
    const float uxb = (float)w * C;

    #pragma unroll
    for (int k = 0; k < 4; ++k) {
        const int h = h0 + k;
        const int dy0 = max((h - 1) >> 1, 0);
        const int dy1 = min((h + 1) >> 1, 511);
        const float ty = (h & 1) ? 0.25f : 0.75f;
        const float* r0 = rbase + (dy0 << 9);
        const float* r1 = rbase + (dy1 << 9);

        float a0 = r0[dx0], b0 = r0[dx1];
        float a1 = r1[dx0], b1 = r1[dx1];
        float m0 = fmaf(b0 - a0, tx, a0);
        float m1 = fmaf(b1 - a1, tx, a1);
        float ds = fmaf(m1 - m0, ty, m0);

        // sample coords (+0.5 folded); |displacement| <= ~21 px
        float ux = fmaf(ds, scx, uxb);
        float uy = fmaf(ds, scy, (float)h * C);

        // reflect: single fold valid for u in (-2048, 2048)
        ux = fabsf(ux); if (ux >= 1024.0f) ux = 2048.0f - ux;
        uy = fabsf(uy); if (uy >= 1024.0f) uy = 2048.0f - uy;
        float ix = fminf(fmaxf(ux - 0.5f, 0.0f), 1023.0f);
        float iy = fminf(fmaxf(uy - 0.5f, 0.0f), 1023.0f);

        // bilinear gather
        int ix0 = (int)ix;               // ix >= 0 -> trunc == floor
        int iy0 = (int)iy;
        float wx = ix - (float)ix0;
        float wy = iy - (float)iy0;
        int ix1 = min(ix0 + 1, 1023);
        int iy1 = min(iy0 + 1, 1023);

        const float* Ia = ibase + ((iy0 << 10) + ix0) * 3;
        const float* Ib = ibase + ((iy0 << 10) + ix1) * 3;
        const float* Ic = ibase + ((iy1 << 10) + ix0) * 3;
        const float* Id = ibase + ((iy1 << 10) + ix1) * 3;

        const float wa = (1.0f - wx) * (1.0f - wy);
        const float wb = wx * (1.0f - wy);
        const float wc = (1.0f - wx) * wy;
        const float wd = wx * wy;

        float* o = out + (((long long)(n << 10 | h) << 10) + w) * 3;
        o[0] = Ia[0] * wa + Ib[0] * wb + Ic[0] * wc + Id[0] * wd;
        o[1] = Ia[1] * wa + Ib[1] * wb + Ic[1] * wc + Id[1] * wd;
        o[2] = Ia[2] * wa + Ib[2] * wb + Ic[2] * wc + Id[2] * wd;
    }
}

// ---------------------------------------------------------------------------
// Generic fallback (R0 kernel, proven correct) for other shapes.
// ---------------------------------------------------------------------------
__device__ __forceinline__ float reflect_dyn(float x, float size) {
    x += 0.5f;
    float two = 2.0f * size;
    x = x - floorf(x / two) * two;
    if (x >= size) x = two - x;
    x -= 0.5f;
    return fminf(fmaxf(x, 0.0f), size - 1.0f);
}

__global__ __launch_bounds__(256) void displace_fallback(
    const float* __restrict__ img, const float* __restrict__ dmap,
    const float* __restrict__ amp, const float* __restrict__ ang,
    float* __restrict__ out, int N, int H, int W, int DH, int DW)
{
    long long idx = (long long)blockIdx.x * blockDim.x + threadIdx.x;
    long long total = (long long)N * H * W;
    if (idx >= total) return;
    int w = (int)(idx % W);
    long long t = idx / W;
    int h = (int)(t % H);
    int n = (int)(t / H);

    float sx = (w + 0.5f) * ((float)DW / (float)W) - 0.5f;
    float sy = (h + 0.5f) * ((float)DH / (float)H) - 0.5f;
    float fx = floorf(sx), fy = floorf(sy);
    float tx = sx - fx, ty = sy - fy;
    int dx0 = max(0, min(DW - 1, (int)fx));
    int dx1 = max(0, min(DW - 1, (int)fx + 1));
    int dy0 = max(0, min(DH - 1, (int)fy));
    int dy1 = max(0, min(DH - 1, (int)fy + 1));
    const float* dbase = dmap + (long long)n * DH * DW * 3;
    const float* p00 = dbase + ((long long)dy0 * DW + dx0) * 3;
    const float* p01 = dbase + ((long long)dy0 * DW + dx1) * 3;
    const float* p10 = dbase + ((long long)dy1 * DW + dx0) * 3;
    const float* p11 = dbase + ((long long)dy1 * DW + dx1) * 3;
    float m00 = p00[0] + p00[1] + p00[2];
    float m01 = p01[0] + p01[1] + p01[2];
    float m10 = p10[0] + p10[1] + p10[2];
    float m11 = p11[0] + p11[1] + p11[2];
    float dmv = ((m00 * (1.0f - tx) + m01 * tx) * (1.0f - ty)
               + (m10 * (1.0f - tx) + m11 * tx) * ty) * (1.0f / 3.0f);
    float a = amp[n], an = ang[n], sa, ca;
    sincosf(an, &sa, &ca);
    float d = dmv * a;
    float gx = -1.0f + 2.0f * (float)w / (float)(W - 1) + ca * d * (2.0f / (float)(W - 1));
    float gy = -1.0f + 2.0f * (float)h / (float)(H - 1) + sa * d * (2.0f / (float)(H - 1));
    float ixf2 = ((gx + 1.0f) * (float)W - 1.0f) * 0.5f;
    float iyf2 = ((gy + 1.0f) * (float)H - 1.0f) * 0.5f;
    ixf2 = reflect_dyn(ixf2, (float)W);
    iyf2 = reflect_dyn(iyf2, (float)H);
    float x0f = floorf(ixf2), y0f = floorf(iyf2);
    float wx = ixf2 - x0f, wy = iyf2 - y0f;
    int ix0 = min((int)x0f, W - 1);
    int ix1 = min((int)x0f + 1, W - 1);
    int iy0 = min((int)y0f, H - 1);
    int iy1 = min((int)y0f + 1, H - 1);
    const float* ibase = img + (long long)n * H * W * 3;
    const float* Ia = ibase + ((long long)iy0 * W + ix0) * 3;
    const float* Ib = ibase + ((long long)iy0 * W + ix1) * 3;
    const float* Ic = ibase + ((long long)iy1 * W + ix0) * 3;
    const float* Id = ibase + ((long long)iy1 * W + ix1) * 3;
    float wa = (1.0f - wx) * (1.0f - wy);
    float wb = wx * (1.0f - wy);
    float wc = (1.0f - wx) * wy;
    float wd = wx * wy;
    float* o = out + idx * 3;
    #pragma unroll
    for (int c = 0; c < 3; ++c)
        o[c] = Ia[c] * wa + Ib[c] * wb + Ic[c] * wc + Id[c] * wd;
}

extern "C" void kernel_launch(void* const* d_in, const int* in_sizes, int n_in,
                              void* d_out, int out_size, void* d_ws, size_t ws_size,
                              hipStream_t stream) {
    const float* img  = (const float*)d_in[0];
    const float* dmap = (const float*)d_in[1];
    const float* amp  = (const float*)d_in[2];
    const float* ang  = (const float*)d_in[3];
    float* out = (float*)d_out;

    int N = in_sizes[2];
    long long hw  = (long long)in_sizes[0] / ((long long)N * 3);
    int H = (int)llround(sqrt((double)hw));
    int W = H;
    long long dhw = (long long)in_sizes[1] / ((long long)N * 3);
    int DH = (int)llround(sqrt((double)dhw));
    int DW = DH;

    size_t need = 256 + (size_t)N * DH * DW * sizeof(float);

    if (H == 1024 && W == 1024 && DH == 512 && DW == 512 && N == 8 &&
        ws_size >= need) {
        float* sc = (float*)d_ws;
        float* rd = (float*)((char*)d_ws + 256);

        long long npix = (long long)N * DH * DW;
        int pgrid = (int)((npix + 255) / 256);
        prep_kernel<<<pgrid, 256, 0, stream>>>(
            dmap, amp, ang, sc, rd, npix, N,
            (float)W / (float)(W - 1), (float)H / (float)(H - 1));

        // 8 images * (4 w-chunks * 256 row-groups) = 8192 blocks of 256
        displace_main<<<8192, 256, 0, stream>>>(img, rd, sc, out);
    } else {
        long long total = (long long)N * H * W;
        int block = 256;
        long long grid = (total + block - 1) / block;
        displace_fallback<<<(dim3)(unsigned)grid, block, 0, stream>>>(
            img, dmap, amp, ang, out, N, H, W, DH, DW);
    }
}